// Round 3
// baseline (4039.410 us; speedup 1.0000x reference)
//
#include <hip/hip_runtime.h>
#include <hip/hip_bf16.h>

#define EPSF 1e-5f

// ============================================================================
// Prelude kernels (small, total d_ws use = 7.06 MB)
// ============================================================================

// GroupNorm stats. x is (16,256,4096); group = 64 ch = 262144 contiguous floats.
__global__ __launch_bounds__(256) void gn_stats_partial(const float* __restrict__ x,
                                                        float* __restrict__ part) {
    int blk = blockIdx.x;             // 1024 = 64 (b,g) * 16 subs
    int bg  = blk >> 4, sub = blk & 15;
    int t   = threadIdx.x;
    const float4* p = (const float4*)(x + bg * 262144 + sub * 16384);
    float s = 0.f, q = 0.f;
#pragma unroll
    for (int i = 0; i < 16; i++) {
        float4 v = p[i * 256 + t];
        s += v.x + v.y + v.z + v.w;
        q += v.x * v.x + v.y * v.y + v.z * v.z + v.w * v.w;
    }
    __shared__ float red[8];
#pragma unroll
    for (int off = 32; off; off >>= 1) { s += __shfl_down(s, off); q += __shfl_down(q, off); }
    int lane = t & 63, w = t >> 6;
    if (lane == 0) { red[w * 2] = s; red[w * 2 + 1] = q; }
    __syncthreads();
    if (t == 0) {
        part[blk * 2]     = red[0] + red[2] + red[4] + red[6];
        part[blk * 2 + 1] = red[1] + red[3] + red[5] + red[7];
    }
}

__global__ void gn_stats_final(const float* __restrict__ part, float* __restrict__ stats) {
    int g = threadIdx.x;   // 64 threads
    float s = 0.f, q = 0.f;
    for (int i = 0; i < 16; i++) { s += part[(g * 16 + i) * 2]; q += part[(g * 16 + i) * 2 + 1]; }
    float m   = s * (1.f / 262144.f);
    float var = q * (1.f / 262144.f) - m * m;
    stats[g]      = m;
    stats[64 + g] = rsqrtf(var + EPSF);
}

// gp = style @ Wg + bg (16x512); tmp_s = style @ Ws + bs (16x256)
__global__ __launch_bounds__(256) void styleproj_kernel(const float* __restrict__ style,
                                                        const float* __restrict__ Wg,
                                                        const float* __restrict__ bg,
                                                        const float* __restrict__ Ws,
                                                        const float* __restrict__ bs,
                                                        float* __restrict__ gp,
                                                        float* __restrict__ tmp_s) {
    __shared__ float st[512];
    int blk = blockIdx.x;              // 48 blocks
    int b = blk / 3, part = blk % 3, t = threadIdx.x;
    st[t] = style[b * 512 + t];
    st[256 + t] = style[b * 512 + 256 + t];
    __syncthreads();
    if (part < 2) {
        int c = part * 256 + t;
        float acc = 0.f;
        for (int i = 0; i < 512; i++) acc += st[i] * Wg[i * 512 + c];
        gp[b * 512 + c] = acc + bg[c];
    } else {
        float acc = 0.f;
        for (int i = 0; i < 512; i++) acc += st[i] * Ws[i * 256 + t];
        tmp_s[b * 256 + t] = acc + bs[t];
    }
}

// tok = LN(tokens + tmp_s)
__global__ __launch_bounds__(256) void tok_kernel(const float* __restrict__ tokens,
                                                  const float* __restrict__ tmp_s,
                                                  const float* __restrict__ g,
                                                  const float* __restrict__ bta,
                                                  float* __restrict__ tok) {
    __shared__ float red[8];
    int blk = blockIdx.x;              // 1024 = 16*64
    int b = blk >> 6, tk = blk & 63, t = threadIdx.x;
    float val = tokens[tk * 256 + t] + tmp_s[b * 256 + t];
    float s = val, q = val * val;
#pragma unroll
    for (int off = 32; off; off >>= 1) { s += __shfl_down(s, off); q += __shfl_down(q, off); }
    int lane = t & 63, w = t >> 6;
    if (lane == 0) { red[w * 2] = s; red[w * 2 + 1] = q; }
    __syncthreads();
    s = red[0] + red[2] + red[4] + red[6];
    q = red[1] + red[3] + red[5] + red[7];
    float m = s * (1.f / 256.f);
    float var = q * (1.f / 256.f) - m * m;
    float r = rsqrtf(var + EPSF);
    tok[(b * 64 + tk) * 256 + t] = (val - m) * r * g[t] + bta[t];
}

// k = tok@Wk+bk, v = tok@Wv+bv
__global__ __launch_bounds__(256) void kv_kernel(const float* __restrict__ tok,
                                                 const float* __restrict__ Wk,
                                                 const float* __restrict__ bk,
                                                 const float* __restrict__ Wv,
                                                 const float* __restrict__ bv,
                                                 float* __restrict__ kb,
                                                 float* __restrict__ vb) {
    __shared__ float tr[256];
    int blk = blockIdx.x, t = threadIdx.x;   // 1024 blocks
    tr[t] = tok[blk * 256 + t];
    __syncthreads();
    float ak = 0.f, av = 0.f;
    for (int i = 0; i < 256; i++) {
        float tv = tr[i];
        ak += tv * Wk[i * 256 + t];
        av += tv * Wv[i * 256 + t];
    }
    kb[blk * 256 + t] = ak + bk[t];
    vb[blk * 256 + t] = av + bv[t];
}

// pos_emb = silu(coords@Wp1 + bp1) @ Wp2 + bp2   (4096 x 256)
__global__ __launch_bounds__(256) void pos_kernel(const float* __restrict__ Wp1,
                                                  const float* __restrict__ bp1,
                                                  const float* __restrict__ Wp2,
                                                  const float* __restrict__ bp2,
                                                  float* __restrict__ pos) {
    __shared__ float pe[256];
    int s = blockIdx.x, t = threadIdx.x;     // 4096 blocks
    float gx = -1.f + 2.f * (float)(s & 63) * (1.f / 63.f);
    float gy = -1.f + 2.f * (float)(s >> 6) * (1.f / 63.f);
    float h = gx * Wp1[t] + gy * Wp1[256 + t] + bp1[t];
    pe[t] = h / (1.f + __expf(-h));
    __syncthreads();
    float acc = 0.f;
    for (int i = 0; i < 256; i++) acc += pe[i] * Wp2[i * 256 + t];
    pos[s * 256 + t] = acc + bp2[t];
}

// ============================================================================
// Mega kernel: one block = (b, 32-row s-tile). Everything after GN is row-local.
// LDS = 62,336 B.  Writes d_out exactly once (no global intermediates).
// ============================================================================
#define ASTR 257   // As stride: 257 % 32 == 1 -> (row + c) % 32, conflict-free col reads

__global__ __launch_bounds__(256) void mega_kernel(
    const float* __restrict__ x, const float* __restrict__ stats,
    const float* __restrict__ pos, const float* __restrict__ kbuf,
    const float* __restrict__ vbuf, const float* __restrict__ gp,
    const float* __restrict__ lnq_g, const float* __restrict__ lnq_b,
    const float* __restrict__ lnf_g, const float* __restrict__ lnf_b,
    const float* __restrict__ Wq, const float* __restrict__ bq,
    const float* __restrict__ Wo, const float* __restrict__ bo,
    const float* __restrict__ Wf1, const float* __restrict__ bf1,
    const float* __restrict__ Wf2, const float* __restrict__ bf2,
    const float* __restrict__ gamma, float* __restrict__ out)
{
    __shared__ float As[32 * ASTR];    // 32896 B — the 32x256 working tile
    __shared__ float scr[6272];        // 25088 B — ks(64x65) + S(32x66) | h1 chunk | bounce
    __shared__ float lg[256], lb[256]; // ln_f gamma/beta staged
    __shared__ float psum[256], psq[256];
    __shared__ float rowred[64];       // per-row (m, rstd)

    const int blk = blockIdx.x;        // 2048 = 16 b * 128 tiles
    const int b   = blk >> 7;
    const int s0  = (blk & 127) * 32;
    const int t   = threadIdx.x;

    lg[t] = lnf_g[t]; lb[t] = lnf_b[t];

    // ---- S1: As[i][c] = GN(x)[b, c, s0+i] + pos[s0+i][c], then row-LN --------
    const float mg = stats[b * 4 + (t >> 6)];
    const float rg = stats[64 + b * 4 + (t >> 6)];
    {
        const float4* xp = (const float4*)(x + (size_t)(b * 256 + t) * 4096 + s0);
        float xv[32];
#pragma unroll
        for (int i = 0; i < 8; i++) {
            float4 v = xp[i];
            xv[4*i] = v.x; xv[4*i+1] = v.y; xv[4*i+2] = v.z; xv[4*i+3] = v.w;
        }
#pragma unroll
        for (int i = 0; i < 32; i++) {
            float pv = pos[(size_t)(s0 + i) * 256 + t];
            As[i * ASTR + t] = (xv[i] - mg) * rg + pv;
        }
    }
    __syncthreads();
    {   // row stats (mean/var over c)
        int sl = t & 31, cg = t >> 5;
        float s = 0.f, q = 0.f;
#pragma unroll
        for (int cc = 0; cc < 32; cc++) {
            float v = As[sl * ASTR + cg * 32 + cc];
            s += v; q += v * v;
        }
        psum[cg * 32 + sl] = s; psq[cg * 32 + sl] = q;
    }
    __syncthreads();
    if (t < 32) {
        float S = 0.f, Q = 0.f;
        for (int p = 0; p < 8; p++) { S += psum[p * 32 + t]; Q += psq[p * 32 + t]; }
        float m = S * (1.f / 256.f);
        float var = Q * (1.f / 256.f) - m * m;
        rowred[t * 2] = m; rowred[t * 2 + 1] = rsqrtf(var + EPSF);
    }
    __syncthreads();
    {
        float gq = lnq_g[t], bqv = lnq_b[t];
#pragma unroll
        for (int i = 0; i < 32; i++)
            As[i * ASTR + t] = (As[i * ASTR + t] - rowred[i * 2]) * rowred[i * 2 + 1] * gq + bqv;
    }
    __syncthreads();

    // ---- S2: q = As @ Wq + bq  (overwrite As) --------------------------------
    {
        int cx = (t & 63) * 4, ry = (t >> 6) * 8;
        float acc[8][4];
#pragma unroll
        for (int r = 0; r < 8; r++) for (int j = 0; j < 4; j++) acc[r][j] = 0.f;
#pragma unroll 4
        for (int k = 0; k < 256; k++) {
            float4 wv = *(const float4*)&Wq[k * 256 + cx];
#pragma unroll
            for (int r = 0; r < 8; r++) {
                float a = As[(ry + r) * ASTR + k];
                acc[r][0] += a * wv.x; acc[r][1] += a * wv.y;
                acc[r][2] += a * wv.z; acc[r][3] += a * wv.w;
            }
        }
        __syncthreads();   // all As reads done before overwrite
        float4 bv = *(const float4*)&bq[cx];
#pragma unroll
        for (int r = 0; r < 8; r++) {
            As[(ry + r) * ASTR + cx + 0] = acc[r][0] + bv.x;
            As[(ry + r) * ASTR + cx + 1] = acc[r][1] + bv.y;
            As[(ry + r) * ASTR + cx + 2] = acc[r][2] + bv.z;
            As[(ry + r) * ASTR + cx + 3] = acc[r][3] + bv.w;
        }
    }
    __syncthreads();

    // ---- S3: attention vs 64 tokens, per head; O_h overwrites q_h cols -------
    float* ks = scr;            // 64*65 = 4160 floats (K, then V)
    float* Ss = scr + 4160;     // 32*66 = 2112 floats (scores)
    for (int h = 0; h < 4; h++) {
#pragma unroll
        for (int ch = 0; ch < 16; ch++) {           // load K_h (64x64)
            int e = ch * 256 + t, j = e >> 6, d = e & 63;
            ks[j * 65 + d] = kbuf[(size_t)(b * 64 + j) * 256 + h * 64 + d];
        }
        __syncthreads();
        {   // scores S = q_h @ K_h^T * 0.25
            int it = t & 31, jg = t >> 5;
            float sc8[8];
#pragma unroll
            for (int jj = 0; jj < 8; jj++) sc8[jj] = 0.f;
            for (int d = 0; d < 64; d++) {
                float qv = As[it * ASTR + h * 64 + d];
#pragma unroll
                for (int jj = 0; jj < 8; jj++) sc8[jj] += qv * ks[(jg * 8 + jj) * 65 + d];
            }
#pragma unroll
            for (int jj = 0; jj < 8; jj++) Ss[it * 66 + jg * 8 + jj] = sc8[jj] * 0.25f;
        }
        __syncthreads();
        if (t < 32) {   // softmax per row
            float mx = -1e30f;
            for (int j = 0; j < 64; j++) mx = fmaxf(mx, Ss[t * 66 + j]);
            float sum = 0.f;
            for (int j = 0; j < 64; j++) { float e = __expf(Ss[t * 66 + j] - mx); Ss[t * 66 + j] = e; sum += e; }
            float inv = 1.f / sum;
            for (int j = 0; j < 64; j++) Ss[t * 66 + j] *= inv;
        }
#pragma unroll
        for (int ch = 0; ch < 16; ch++) {           // load V_h into ks slot (K reads done)
            int e = ch * 256 + t, j = e >> 6, d = e & 63;
            ks[j * 65 + d] = vbuf[(size_t)(b * 64 + j) * 256 + h * 64 + d];
        }
        __syncthreads();
        {   // O_h = P @ V_h -> overwrite As cols [h*64, h*64+64)
            int it = t & 31, dg = t >> 5;
            float oa[8];
#pragma unroll
            for (int jj = 0; jj < 8; jj++) oa[jj] = 0.f;
            for (int j = 0; j < 64; j++) {
                float pv = Ss[it * 66 + j];
#pragma unroll
                for (int jj = 0; jj < 8; jj++) oa[jj] += pv * ks[j * 65 + dg * 8 + jj];
            }
#pragma unroll
            for (int jj = 0; jj < 8; jj++) As[it * ASTR + h * 64 + dg * 8 + jj] = oa[jj];
        }
        __syncthreads();
    }

    // ---- S4: sc = AttnOut @ Wo + bo  (overwrite As) --------------------------
    {
        int cx = (t & 63) * 4, ry = (t >> 6) * 8;
        float acc[8][4];
#pragma unroll
        for (int r = 0; r < 8; r++) for (int j = 0; j < 4; j++) acc[r][j] = 0.f;
#pragma unroll 4
        for (int k = 0; k < 256; k++) {
            float4 wv = *(const float4*)&Wo[k * 256 + cx];
#pragma unroll
            for (int r = 0; r < 8; r++) {
                float a = As[(ry + r) * ASTR + k];
                acc[r][0] += a * wv.x; acc[r][1] += a * wv.y;
                acc[r][2] += a * wv.z; acc[r][3] += a * wv.w;
            }
        }
        __syncthreads();
        float4 bv = *(const float4*)&bo[cx];
#pragma unroll
        for (int r = 0; r < 8; r++) {
            As[(ry + r) * ASTR + cx + 0] = acc[r][0] + bv.x;
            As[(ry + r) * ASTR + cx + 1] = acc[r][1] + bv.y;
            As[(ry + r) * ASTR + cx + 2] = acc[r][2] + bv.z;
            As[(ry + r) * ASTR + cx + 3] = acc[r][3] + bv.w;
        }
    }
    __syncthreads();

    // ---- S5: FFN. LN stats on sc rows; h1 in 64-col chunks; acc2 in regs -----
    {
        int sl = t & 31, cg = t >> 5;
        float s = 0.f, q = 0.f;
#pragma unroll
        for (int cc = 0; cc < 32; cc++) {
            float v = As[sl * ASTR + cg * 32 + cc];
            s += v; q += v * v;
        }
        psum[cg * 32 + sl] = s; psq[cg * 32 + sl] = q;
    }
    __syncthreads();
    if (t < 32) {
        float S = 0.f, Q = 0.f;
        for (int p = 0; p < 8; p++) { S += psum[p * 32 + t]; Q += psq[p * 32 + t]; }
        float m = S * (1.f / 256.f);
        float var = Q * (1.f / 256.f) - m * m;
        rowred[t * 2] = m; rowred[t * 2 + 1] = rsqrtf(var + EPSF);
    }
    __syncthreads();

    float* h1c = scr;           // 32*66 = 2112 floats per chunk
    const int cx2 = (t & 63) * 4, ry2 = (t >> 6) * 8;   // GEMM2 layout
    const int colx = (t & 15) * 4, rowy = (t >> 4) * 2; // GEMM1 layout
    const float m0 = rowred[rowy * 2],       r0 = rowred[rowy * 2 + 1];
    const float m1 = rowred[(rowy + 1) * 2], r1 = rowred[(rowy + 1) * 2 + 1];
    float acc2[8][4];
#pragma unroll
    for (int r = 0; r < 8; r++) for (int j = 0; j < 4; j++) acc2[r][j] = 0.f;

    for (int cc = 0; cc < 8; cc++) {
        float a1[2][4];
#pragma unroll
        for (int r = 0; r < 2; r++) for (int j = 0; j < 4; j++) a1[r][j] = 0.f;
#pragma unroll 2
        for (int k = 0; k < 256; k++) {
            float gk = lg[k], bk = lb[k];
            float4 wv = *(const float4*)&Wf1[k * 512 + cc * 64 + colx];
            float a0 = (As[rowy * ASTR + k] - m0) * r0 * gk + bk;
            float b0 = (As[(rowy + 1) * ASTR + k] - m1) * r1 * gk + bk;
            a1[0][0] += a0 * wv.x; a1[0][1] += a0 * wv.y; a1[0][2] += a0 * wv.z; a1[0][3] += a0 * wv.w;
            a1[1][0] += b0 * wv.x; a1[1][1] += b0 * wv.y; a1[1][2] += b0 * wv.z; a1[1][3] += b0 * wv.w;
        }
        __syncthreads();   // previous chunk's h1c reads complete
        {
            float4 b1 = *(const float4*)&bf1[cc * 64 + colx];
#pragma unroll
            for (int r = 0; r < 2; r++) {
                float h0 = a1[r][0] + b1.x, h1v = a1[r][1] + b1.y;
                float h2 = a1[r][2] + b1.z, h3 = a1[r][3] + b1.w;
                h1c[(rowy + r) * 66 + colx + 0] = h0 / (1.f + __expf(-h0));
                h1c[(rowy + r) * 66 + colx + 1] = h1v / (1.f + __expf(-h1v));
                h1c[(rowy + r) * 66 + colx + 2] = h2 / (1.f + __expf(-h2));
                h1c[(rowy + r) * 66 + colx + 3] = h3 / (1.f + __expf(-h3));
            }
        }
        __syncthreads();
#pragma unroll 2
        for (int kk = 0; kk < 64; kk++) {
            float4 wv = *(const float4*)&Wf2[(cc * 64 + kk) * 256 + cx2];
#pragma unroll
            for (int r = 0; r < 8; r++) {
                float a = h1c[(ry2 + r) * 66 + kk];
                acc2[r][0] += a * wv.x; acc2[r][1] += a * wv.y;
                acc2[r][2] += a * wv.z; acc2[r][3] += a * wv.w;
            }
        }
    }
    __syncthreads();   // h1c dead; scr becomes bounce

    // ---- S6: final = GN(x)*scale + shift + sc_final*gamma, transposed write --
    float* bounce = scr;   // 16*260 floats per half
    const float scl = gp[b * 512 + t];
    const float sft = gp[b * 512 + 256 + t];
    const float gm  = gamma[t];
    const float4 bv2 = *(const float4*)&bf2[cx2];
    for (int half = 0; half < 2; half++) {
#pragma unroll
        for (int r = 0; r < 8; r++) {
            int row = ry2 + r;
            if ((row >> 4) == half) {
                int rl = row & 15;
                bounce[rl * 260 + cx2 + 0] = acc2[r][0] + bv2.x + As[row * ASTR + cx2 + 0];
                bounce[rl * 260 + cx2 + 1] = acc2[r][1] + bv2.y + As[row * ASTR + cx2 + 1];
                bounce[rl * 260 + cx2 + 2] = acc2[r][2] + bv2.z + As[row * ASTR + cx2 + 2];
                bounce[rl * 260 + cx2 + 3] = acc2[r][3] + bv2.w + As[row * ASTR + cx2 + 3];
            }
        }
        __syncthreads();
        {
            const float4* xp = (const float4*)(x + (size_t)(b * 256 + t) * 4096 + s0 + half * 16);
            float4* op = (float4*)(out + (size_t)(b * 256 + t) * 4096 + s0 + half * 16);
#pragma unroll
            for (int ii = 0; ii < 4; ii++) {
                float4 xv = xp[ii];
                float4 o;
                o.x = (xv.x - mg) * rg * scl + sft + bounce[(ii * 4 + 0) * 260 + t] * gm;
                o.y = (xv.y - mg) * rg * scl + sft + bounce[(ii * 4 + 1) * 260 + t] * gm;
                o.z = (xv.z - mg) * rg * scl + sft + bounce[(ii * 4 + 2) * 260 + t] * gm;
                o.w = (xv.w - mg) * rg * scl + sft + bounce[(ii * 4 + 3) * 260 + t] * gm;
                op[ii] = o;
            }
        }
        __syncthreads();
    }
}

// ============================================================================
extern "C" void kernel_launch(void* const* d_in, const int* in_sizes, int n_in,
                              void* d_out, int out_size, void* d_ws, size_t ws_size,
                              hipStream_t stream) {
    (void)in_sizes; (void)n_in; (void)out_size; (void)ws_size;
    const float* x      = (const float*)d_in[0];
    const float* style  = (const float*)d_in[1];
    const float* Wg     = (const float*)d_in[2];
    const float* bg     = (const float*)d_in[3];
    const float* tokens = (const float*)d_in[4];
    const float* Ws     = (const float*)d_in[5];
    const float* bs     = (const float*)d_in[6];
    const float* Wp1    = (const float*)d_in[7];
    const float* bp1    = (const float*)d_in[8];
    const float* Wp2    = (const float*)d_in[9];
    const float* bp2    = (const float*)d_in[10];
    const float* ln_t_g = (const float*)d_in[11];
    const float* ln_t_b = (const float*)d_in[12];
    const float* ln_q_g = (const float*)d_in[13];
    const float* ln_q_b = (const float*)d_in[14];
    const float* ln_f_g = (const float*)d_in[15];
    const float* ln_f_b = (const float*)d_in[16];
    const float* Wq     = (const float*)d_in[17];
    const float* bq     = (const float*)d_in[18];
    const float* Wk     = (const float*)d_in[19];
    const float* bk     = (const float*)d_in[20];
    const float* Wv     = (const float*)d_in[21];
    const float* bv     = (const float*)d_in[22];
    const float* Wo     = (const float*)d_in[23];
    const float* bo     = (const float*)d_in[24];
    const float* Wf1    = (const float*)d_in[25];
    const float* bf1    = (const float*)d_in[26];
    const float* Wf2    = (const float*)d_in[27];
    const float* bf2    = (const float*)d_in[28];
    const float* gamma  = (const float*)d_in[29];
    float* out = (float*)d_out;

    // d_ws layout: 1,849,472 floats = 7.06 MB total
    float* ws = (float*)d_ws;
    float* part  = ws;              // 2048
    float* stats = part  + 2048;    // 128
    float* gpb   = stats + 128;     // 8192
    float* tmp_s = gpb   + 8192;    // 4096
    float* tokb  = tmp_s + 4096;    // 262144
    float* kbuf  = tokb  + 262144;  // 262144
    float* vbuf  = kbuf  + 262144;  // 262144
    float* posb  = vbuf  + 262144;  // 1048576

    gn_stats_partial<<<1024, 256, 0, stream>>>(x, part);
    gn_stats_final<<<1, 64, 0, stream>>>(part, stats);
    styleproj_kernel<<<48, 256, 0, stream>>>(style, Wg, bg, Ws, bs, gpb, tmp_s);
    tok_kernel<<<1024, 256, 0, stream>>>(tokens, tmp_s, ln_t_g, ln_t_b, tokb);
    kv_kernel<<<1024, 256, 0, stream>>>(tokb, Wk, bk, Wv, bv, kbuf, vbuf);
    pos_kernel<<<4096, 256, 0, stream>>>(Wp1, bp1, Wp2, bp2, posb);
    mega_kernel<<<2048, 256, 0, stream>>>(x, stats, posb, kbuf, vbuf, gpb,
                                          ln_q_g, ln_q_b, ln_f_g, ln_f_b,
                                          Wq, bq, Wo, bo, Wf1, bf1, Wf2, bf2,
                                          gamma, out);
}

// Round 4
// 672.987 us; speedup vs baseline: 6.0022x; 6.0022x over previous
//
#include <hip/hip_runtime.h>
#include <hip/hip_bf16.h>

#define EPSF 1e-5f

typedef __bf16 bf16x8 __attribute__((ext_vector_type(8)));
typedef float  f32x4  __attribute__((ext_vector_type(4)));
#define MFMA16(a, b, c) __builtin_amdgcn_mfma_f32_16x16x32_bf16((a), (b), (c), 0, 0, 0)

__device__ __forceinline__ bf16x8 ld_bf8(const __bf16* p) { return *(const bf16x8*)p; }

__device__ __forceinline__ unsigned short f2bf(float x) {
    unsigned int u = __float_as_uint(x);
    unsigned int r = (u + 0x7fffu + ((u >> 16) & 1u)) >> 16;
    return (unsigned short)r;
}

// ============================================================================
// Prelude kernels
// ============================================================================

__global__ __launch_bounds__(256) void gn_stats_partial(const float* __restrict__ x,
                                                        float* __restrict__ part) {
    int blk = blockIdx.x;             // 1024 = 64 (b,g) * 16 subs
    int bg  = blk >> 4, sub = blk & 15;
    int t   = threadIdx.x;
    const float4* p = (const float4*)(x + bg * 262144 + sub * 16384);
    float s = 0.f, q = 0.f;
#pragma unroll
    for (int i = 0; i < 16; i++) {
        float4 v = p[i * 256 + t];
        s += v.x + v.y + v.z + v.w;
        q += v.x * v.x + v.y * v.y + v.z * v.z + v.w * v.w;
    }
    __shared__ float red[8];
#pragma unroll
    for (int off = 32; off; off >>= 1) { s += __shfl_down(s, off); q += __shfl_down(q, off); }
    int lane = t & 63, w = t >> 6;
    if (lane == 0) { red[w * 2] = s; red[w * 2 + 1] = q; }
    __syncthreads();
    if (t == 0) {
        part[blk * 2]     = red[0] + red[2] + red[4] + red[6];
        part[blk * 2 + 1] = red[1] + red[3] + red[5] + red[7];
    }
}

__global__ void gn_stats_final(const float* __restrict__ part, float* __restrict__ stats) {
    int g = threadIdx.x;   // 64
    float s = 0.f, q = 0.f;
    for (int i = 0; i < 16; i++) { s += part[(g * 16 + i) * 2]; q += part[(g * 16 + i) * 2 + 1]; }
    float m   = s * (1.f / 262144.f);
    float var = q * (1.f / 262144.f) - m * m;
    stats[g]      = m;
    stats[64 + g] = rsqrtf(var + EPSF);
}

__global__ __launch_bounds__(256) void styleproj_kernel(const float* __restrict__ style,
                                                        const float* __restrict__ Wg,
                                                        const float* __restrict__ bg,
                                                        const float* __restrict__ Ws,
                                                        const float* __restrict__ bs,
                                                        float* __restrict__ gp,
                                                        float* __restrict__ tmp_s) {
    __shared__ float st[512];
    int blk = blockIdx.x;              // 48
    int b = blk / 3, part = blk % 3, t = threadIdx.x;
    st[t] = style[b * 512 + t];
    st[256 + t] = style[b * 512 + 256 + t];
    __syncthreads();
    if (part < 2) {
        int c = part * 256 + t;
        float acc = 0.f;
        for (int i = 0; i < 512; i++) acc += st[i] * Wg[i * 512 + c];
        gp[b * 512 + c] = acc + bg[c];
    } else {
        float acc = 0.f;
        for (int i = 0; i < 512; i++) acc += st[i] * Ws[i * 256 + t];
        tmp_s[b * 256 + t] = acc + bs[t];
    }
}

__global__ __launch_bounds__(256) void tok_kernel(const float* __restrict__ tokens,
                                                  const float* __restrict__ tmp_s,
                                                  const float* __restrict__ g,
                                                  const float* __restrict__ bta,
                                                  float* __restrict__ tok) {
    __shared__ float red[8];
    int blk = blockIdx.x;              // 1024
    int b = blk >> 6, tk = blk & 63, t = threadIdx.x;
    float val = tokens[tk * 256 + t] + tmp_s[b * 256 + t];
    float s = val, q = val * val;
#pragma unroll
    for (int off = 32; off; off >>= 1) { s += __shfl_down(s, off); q += __shfl_down(q, off); }
    int lane = t & 63, w = t >> 6;
    if (lane == 0) { red[w * 2] = s; red[w * 2 + 1] = q; }
    __syncthreads();
    s = red[0] + red[2] + red[4] + red[6];
    q = red[1] + red[3] + red[5] + red[7];
    float m = s * (1.f / 256.f);
    float var = q * (1.f / 256.f) - m * m;
    float r = rsqrtf(var + EPSF);
    tok[(b * 64 + tk) * 256 + t] = (val - m) * r * g[t] + bta[t];
}

// k -> bf16 [tok][256]; v -> transposed bf16 [b][d][tok]
__global__ __launch_bounds__(256) void kv_kernel(const float* __restrict__ tok,
                                                 const float* __restrict__ Wk,
                                                 const float* __restrict__ bk,
                                                 const float* __restrict__ Wv,
                                                 const float* __restrict__ bv,
                                                 unsigned short* __restrict__ kb16,
                                                 unsigned short* __restrict__ vt16) {
    __shared__ float tr[256];
    int blk = blockIdx.x, t = threadIdx.x;   // 1024 = b*64+tok
    int b = blk >> 6, tkn = blk & 63;
    tr[t] = tok[blk * 256 + t];
    __syncthreads();
    float ak = 0.f, av = 0.f;
    for (int i = 0; i < 256; i++) {
        float tv = tr[i];
        ak += tv * Wk[i * 256 + t];
        av += tv * Wv[i * 256 + t];
    }
    kb16[(size_t)blk * 256 + t] = f2bf(ak + bk[t]);
    vt16[((size_t)(b * 256 + t)) * 64 + tkn] = f2bf(av + bv[t]);
}

__global__ __launch_bounds__(256) void pos_kernel(const float* __restrict__ Wp1,
                                                  const float* __restrict__ bp1,
                                                  const float* __restrict__ Wp2,
                                                  const float* __restrict__ bp2,
                                                  float* __restrict__ pos) {
    __shared__ float pe[256];
    int s = blockIdx.x, t = threadIdx.x;     // 4096
    float gx = -1.f + 2.f * (float)(s & 63) * (1.f / 63.f);
    float gy = -1.f + 2.f * (float)(s >> 6) * (1.f / 63.f);
    float h = gx * Wp1[t] + gy * Wp1[256 + t] + bp1[t];
    pe[t] = h / (1.f + __expf(-h));
    __syncthreads();
    float acc = 0.f;
    for (int i = 0; i < 256; i++) acc += pe[i] * Wp2[i * 256 + t];
    pos[s * 256 + t] = acc + bp2[t];
}

// W [K][N] f32 -> Wt [N][K] bf16
__global__ __launch_bounds__(256) void wtrans_kernel(const float* __restrict__ W,
                                                     unsigned short* __restrict__ Wt,
                                                     int K, int N) {
    __shared__ float tile[32][33];
    int ktiles = K >> 5;
    int kt = blockIdx.x % ktiles, nt = blockIdx.x / ktiles;
    int k0 = kt * 32, n0 = nt * 32;
    int tc = threadIdx.x & 31, trr = threadIdx.x >> 5;
#pragma unroll
    for (int j = 0; j < 4; j++) {
        int r = trr + j * 8;
        tile[r][tc] = W[(size_t)(k0 + r) * N + n0 + tc];
    }
    __syncthreads();
#pragma unroll
    for (int j = 0; j < 4; j++) {
        int r = trr + j * 8;      // n-local
        Wt[(size_t)(n0 + r) * K + k0 + tc] = f2bf(tile[tc][r]);
    }
}

// ============================================================================
// Mega kernel (MFMA). One block = (b, 32-row s-tile). LDS = 61,312 B.
// ============================================================================
__global__ __launch_bounds__(256) void mega_kernel(
    const float* __restrict__ x, const float* __restrict__ stats,
    const float* __restrict__ pos,
    const __bf16* __restrict__ kb, const __bf16* __restrict__ vt,
    const float* __restrict__ gp,
    const float* __restrict__ lnq_g, const float* __restrict__ lnq_b,
    const float* __restrict__ lnf_g, const float* __restrict__ lnf_b,
    const __bf16* __restrict__ Wq_t, const float* __restrict__ bq,
    const __bf16* __restrict__ Wo_t, const float* __restrict__ bo,
    const __bf16* __restrict__ Wf1_t, const float* __restrict__ bf1,
    const __bf16* __restrict__ Wf2_t, const float* __restrict__ bf2,
    const float* __restrict__ gamma, float* __restrict__ out)
{
    __shared__ float As[32 * 257];                  // 32,896 B  f32 working tile
    __shared__ __align__(16) __bf16 Ab[32 * 264];   // 16,896 B  bf16 MFMA operand tile
    __shared__ __align__(16) __bf16 Ps[4608];       //  9,216 B  P per wave / FFN h1 bounce
    __shared__ float psum[256], psq[256];           //  2,048 B
    __shared__ float rowred[64];                    //    256 B

    const int blk  = blockIdx.x;        // 2048 = 16 b * 128 tiles
    const int b    = blk >> 7;
    const int s0   = (blk & 127) * 32;
    const int t    = threadIdx.x;
    const int w    = t >> 6;
    const int lane = t & 63;
    const int quad = lane >> 4;
    const int l16  = lane & 15;
    const int mrow  = (w & 1) * 16;     // wave row base (GEMMs / attention)
    const int cbase = (w >> 1) * 128;   // wave col base (256-col GEMMs)

    const float mg = stats[b * 4 + (t >> 6)];
    const float rg = stats[64 + b * 4 + (t >> 6)];

    // ---- S1: As[i][c] = GN(x) + pos; row stats; Ab = bf16(LN(As)) ------------
    {
        const float4* xp = (const float4*)(x + (size_t)(b * 256 + t) * 4096 + s0);
        float xv[32];
#pragma unroll
        for (int i = 0; i < 8; i++) {
            float4 v = xp[i];
            xv[4*i] = v.x; xv[4*i+1] = v.y; xv[4*i+2] = v.z; xv[4*i+3] = v.w;
        }
#pragma unroll
        for (int i = 0; i < 32; i++)
            As[i * 257 + t] = (xv[i] - mg) * rg + pos[(size_t)(s0 + i) * 256 + t];
    }
    __syncthreads();
    {
        int sl = t & 31, cg = t >> 5;
        float s = 0.f, q = 0.f;
#pragma unroll
        for (int cc = 0; cc < 32; cc++) {
            float v = As[sl * 257 + cg * 32 + cc];
            s += v; q += v * v;
        }
        psum[cg * 32 + sl] = s; psq[cg * 32 + sl] = q;
    }
    __syncthreads();
    if (t < 32) {
        float S = 0.f, Q = 0.f;
        for (int p = 0; p < 8; p++) { S += psum[p * 32 + t]; Q += psq[p * 32 + t]; }
        float m = S * (1.f / 256.f);
        float var = Q * (1.f / 256.f) - m * m;
        rowred[t * 2] = m; rowred[t * 2 + 1] = rsqrtf(var + EPSF);
    }
    __syncthreads();
    {
        float gq = lnq_g[t], bqv = lnq_b[t];
#pragma unroll
        for (int i = 0; i < 32; i++)
            Ab[i * 264 + t] = (__bf16)((As[i * 257 + t] - rowred[i * 2]) * rowred[i * 2 + 1] * gq + bqv);
    }
    __syncthreads();

    // ---- S2: Q-proj (MFMA): q = Ab @ Wq + bq -> overwrite Ab -----------------
    {
        bf16x8 af[8];
#pragma unroll
        for (int ks = 0; ks < 8; ks++)
            af[ks] = ld_bf8(&Ab[(mrow + l16) * 264 + ks * 32 + quad * 8]);
        __syncthreads();   // all waves' frags loaded before Ab overwrite
        const f32x4 z4 = {0.f, 0.f, 0.f, 0.f};
#pragma unroll
        for (int nt = 0; nt < 8; nt++) {
            f32x4 acc = z4;
            int n = cbase + nt * 16 + l16;
#pragma unroll
            for (int ks = 0; ks < 8; ks++) {
                bf16x8 bfv = ld_bf8(&Wq_t[(size_t)n * 256 + ks * 32 + quad * 8]);
                acc = MFMA16(af[ks], bfv, acc);
            }
            float bias = bq[n];
#pragma unroll
            for (int r = 0; r < 4; r++)
                Ab[(mrow + quad * 4 + r) * 264 + n] = (__bf16)(acc[r] + bias);
        }
    }
    __syncthreads();

    // ---- S3: attention — wave = (head = w>>1, half = w&1) --------------------
    {
        const int h = w >> 1;
        __bf16* Psw = &Ps[w * 1152];   // 16 x 72
        bf16x8 qa[2];
#pragma unroll
        for (int k0 = 0; k0 < 2; k0++)
            qa[k0] = ld_bf8(&Ab[(mrow + l16) * 264 + h * 64 + k0 * 32 + quad * 8]);
        const f32x4 z4 = {0.f, 0.f, 0.f, 0.f};
        float sc[4][4];   // [nt][r]
#pragma unroll
        for (int nt = 0; nt < 4; nt++) {
            f32x4 acc = z4;
#pragma unroll
            for (int k0 = 0; k0 < 2; k0++) {
                bf16x8 bfv = ld_bf8(&kb[((size_t)(b * 64 + nt * 16 + l16)) * 256 + h * 64 + k0 * 32 + quad * 8]);
                acc = MFMA16(qa[k0], bfv, acc);
            }
#pragma unroll
            for (int r = 0; r < 4; r++) sc[nt][r] = acc[r] * 0.25f;
        }
        // softmax per row (row = quad*4+r); cols spread over 16 lanes x 4 nt
#pragma unroll
        for (int r = 0; r < 4; r++) {
            float mx = fmaxf(fmaxf(sc[0][r], sc[1][r]), fmaxf(sc[2][r], sc[3][r]));
#pragma unroll
            for (int off = 1; off < 16; off <<= 1) mx = fmaxf(mx, __shfl_xor(mx, off));
            float sum = 0.f;
#pragma unroll
            for (int nt = 0; nt < 4; nt++) { sc[nt][r] = __expf(sc[nt][r] - mx); sum += sc[nt][r]; }
#pragma unroll
            for (int off = 1; off < 16; off <<= 1) sum += __shfl_xor(sum, off);
            float inv = 1.f / sum;
#pragma unroll
            for (int nt = 0; nt < 4; nt++) sc[nt][r] *= inv;
        }
#pragma unroll
        for (int nt = 0; nt < 4; nt++)
#pragma unroll
            for (int r = 0; r < 4; r++)
                Psw[(quad * 4 + r) * 72 + nt * 16 + l16] = (__bf16)sc[nt][r];
        __syncthreads();
        // O = P @ V_h -> Ab cols [h*64, h*64+64)
        bf16x8 pa[2];
#pragma unroll
        for (int k0 = 0; k0 < 2; k0++)
            pa[k0] = ld_bf8(&Psw[l16 * 72 + k0 * 32 + quad * 8]);
#pragma unroll
        for (int nt = 0; nt < 4; nt++) {
            f32x4 acc = z4;
#pragma unroll
            for (int k0 = 0; k0 < 2; k0++) {
                bf16x8 bfv = ld_bf8(&vt[((size_t)(b * 256 + h * 64 + nt * 16 + l16)) * 64 + k0 * 32 + quad * 8]);
                acc = MFMA16(pa[k0], bfv, acc);
            }
#pragma unroll
            for (int r = 0; r < 4; r++)
                Ab[(mrow + quad * 4 + r) * 264 + h * 64 + nt * 16 + l16] = (__bf16)acc[r];
        }
    }
    __syncthreads();

    // ---- S4: Wo GEMM (MFMA): sc = Ab @ Wo + bo -> As (f32) -------------------
    {
        bf16x8 af[8];
#pragma unroll
        for (int ks = 0; ks < 8; ks++)
            af[ks] = ld_bf8(&Ab[(mrow + l16) * 264 + ks * 32 + quad * 8]);
        const f32x4 z4 = {0.f, 0.f, 0.f, 0.f};
#pragma unroll
        for (int nt = 0; nt < 8; nt++) {
            f32x4 acc = z4;
            int n = cbase + nt * 16 + l16;
#pragma unroll
            for (int ks = 0; ks < 8; ks++) {
                bf16x8 bfv = ld_bf8(&Wo_t[(size_t)n * 256 + ks * 32 + quad * 8]);
                acc = MFMA16(af[ks], bfv, acc);
            }
            float bias = bo[n];
#pragma unroll
            for (int r = 0; r < 4; r++)
                As[(mrow + quad * 4 + r) * 257 + n] = acc[r] + bias;
        }
    }
    __syncthreads();

    // ---- S5: FFN. row stats on sc; Ab = bf16(LN_f(sc)); 8 x 64-col chunks ----
    {
        int sl = t & 31, cg = t >> 5;
        float s = 0.f, q = 0.f;
#pragma unroll
        for (int cc = 0; cc < 32; cc++) {
            float v = As[sl * 257 + cg * 32 + cc];
            s += v; q += v * v;
        }
        psum[cg * 32 + sl] = s; psq[cg * 32 + sl] = q;
    }
    __syncthreads();
    if (t < 32) {
        float S = 0.f, Q = 0.f;
        for (int p = 0; p < 8; p++) { S += psum[p * 32 + t]; Q += psq[p * 32 + t]; }
        float m = S * (1.f / 256.f);
        float var = Q * (1.f / 256.f) - m * m;
        rowred[t * 2] = m; rowred[t * 2 + 1] = rsqrtf(var + EPSF);
    }
    __syncthreads();
    {
        float gf = lnf_g[t], bfv = lnf_b[t];
#pragma unroll
        for (int i = 0; i < 32; i++)
            Ab[i * 264 + t] = (__bf16)((As[i * 257 + t] - rowred[i * 2]) * rowred[i * 2 + 1] * gf + bfv);
    }
    __syncthreads();
    {
        __bf16* Hb = Ps;   // 32 x 72 bf16 chunk bounce
        bf16x8 fa[8];
#pragma unroll
        for (int ks = 0; ks < 8; ks++)
            fa[ks] = ld_bf8(&Ab[(mrow + l16) * 264 + ks * 32 + quad * 8]);
        const f32x4 z4 = {0.f, 0.f, 0.f, 0.f};
        f32x4 acc2[8];
#pragma unroll
        for (int nt = 0; nt < 8; nt++) acc2[nt] = z4;

        for (int cc = 0; cc < 8; cc++) {
            // FF1 chunk: h1[:, cc*64 .. cc*64+63], wave cols (w>>1)*32 + nt*16
#pragma unroll
            for (int nt = 0; nt < 2; nt++) {
                f32x4 a1 = z4;
                int n = cc * 64 + (w >> 1) * 32 + nt * 16 + l16;
#pragma unroll
                for (int ks = 0; ks < 8; ks++) {
                    bf16x8 bfv = ld_bf8(&Wf1_t[(size_t)n * 256 + ks * 32 + quad * 8]);
                    a1 = MFMA16(fa[ks], bfv, a1);
                }
                float b1 = bf1[n];
                int hc = (w >> 1) * 32 + nt * 16 + l16;
#pragma unroll
                for (int r = 0; r < 4; r++) {
                    float hv = a1[r] + b1;
                    hv = hv / (1.f + __expf(-hv));
                    Hb[(mrow + quad * 4 + r) * 72 + hc] = (__bf16)hv;
                }
            }
            __syncthreads();
            // FF2 accumulate over this 64-K chunk
            bf16x8 ha[2];
#pragma unroll
            for (int k0 = 0; k0 < 2; k0++)
                ha[k0] = ld_bf8(&Hb[(mrow + l16) * 72 + k0 * 32 + quad * 8]);
#pragma unroll
            for (int nt = 0; nt < 8; nt++) {
                int n = cbase + nt * 16 + l16;
#pragma unroll
                for (int k0 = 0; k0 < 2; k0++) {
                    bf16x8 bfv = ld_bf8(&Wf2_t[(size_t)n * 512 + cc * 64 + k0 * 32 + quad * 8]);
                    acc2[nt] = MFMA16(ha[k0], bfv, acc2[nt]);
                }
            }
            __syncthreads();
        }
        // sc_final = sc + h1@Wf2 + bf2  -> As
#pragma unroll
        for (int nt = 0; nt < 8; nt++) {
            int n = cbase + nt * 16 + l16;
            float b2 = bf2[n];
#pragma unroll
            for (int r = 0; r < 4; r++) {
                int idx = (mrow + quad * 4 + r) * 257 + n;
                As[idx] = As[idx] + acc2[nt][r] + b2;
            }
        }
    }
    __syncthreads();

    // ---- S6: out[b,c,s] = GN(x)*scale + shift + sc*gamma ---------------------
    {
        const float scl = gp[b * 512 + t];
        const float sft = gp[b * 512 + 256 + t];
        const float gm  = gamma[t];
        const float4* xp = (const float4*)(x + (size_t)(b * 256 + t) * 4096 + s0);
        float4* op = (float4*)(out + (size_t)(b * 256 + t) * 4096 + s0);
#pragma unroll
        for (int ii = 0; ii < 8; ii++) {
            float4 xv = xp[ii];
            float4 o;
            o.x = (xv.x - mg) * rg * scl + sft + As[(ii * 4 + 0) * 257 + t] * gm;
            o.y = (xv.y - mg) * rg * scl + sft + As[(ii * 4 + 1) * 257 + t] * gm;
            o.z = (xv.z - mg) * rg * scl + sft + As[(ii * 4 + 2) * 257 + t] * gm;
            o.w = (xv.w - mg) * rg * scl + sft + As[(ii * 4 + 3) * 257 + t] * gm;
            op[ii] = o;
        }
    }
}

// ============================================================================
extern "C" void kernel_launch(void* const* d_in, const int* in_sizes, int n_in,
                              void* d_out, int out_size, void* d_ws, size_t ws_size,
                              hipStream_t stream) {
    (void)in_sizes; (void)n_in; (void)out_size; (void)ws_size;
    const float* x      = (const float*)d_in[0];
    const float* style  = (const float*)d_in[1];
    const float* Wg     = (const float*)d_in[2];
    const float* bg     = (const float*)d_in[3];
    const float* tokens = (const float*)d_in[4];
    const float* Ws     = (const float*)d_in[5];
    const float* bs     = (const float*)d_in[6];
    const float* Wp1    = (const float*)d_in[7];
    const float* bp1    = (const float*)d_in[8];
    const float* Wp2    = (const float*)d_in[9];
    const float* bp2    = (const float*)d_in[10];
    const float* ln_t_g = (const float*)d_in[11];
    const float* ln_t_b = (const float*)d_in[12];
    const float* ln_q_g = (const float*)d_in[13];
    const float* ln_q_b = (const float*)d_in[14];
    const float* ln_f_g = (const float*)d_in[15];
    const float* ln_f_b = (const float*)d_in[16];
    const float* Wq     = (const float*)d_in[17];
    const float* bq     = (const float*)d_in[18];
    const float* Wk     = (const float*)d_in[19];
    const float* bk     = (const float*)d_in[20];
    const float* Wv     = (const float*)d_in[21];
    const float* bv     = (const float*)d_in[22];
    const float* Wo     = (const float*)d_in[23];
    const float* bo     = (const float*)d_in[24];
    const float* Wf1    = (const float*)d_in[25];
    const float* bf1    = (const float*)d_in[26];
    const float* Wf2    = (const float*)d_in[27];
    const float* bf2    = (const float*)d_in[28];
    const float* gamma  = (const float*)d_in[29];
    float* out = (float*)d_out;

    // d_ws layout: ~7.1 MB
    float* ws = (float*)d_ws;
    float* part  = ws;               // 2048
    float* stats = part  + 2048;     // 128
    float* gpb   = stats + 128;      // 8192
    float* tmp_s = gpb   + 8192;     // 4096
    float* tokb  = tmp_s + 4096;     // 262144
    float* posb  = tokb  + 262144;   // 1048576
    unsigned short* kb16  = (unsigned short*)(posb + 1048576); // 262144 bf16
    unsigned short* vt16  = kb16  + 262144;                    // 262144
    unsigned short* wq_t  = vt16  + 262144;                    // 65536
    unsigned short* wo_t  = wq_t  + 65536;                     // 65536
    unsigned short* wf1_t = wo_t  + 65536;                     // 131072
    unsigned short* wf2_t = wf1_t + 131072;                    // 131072

    gn_stats_partial<<<1024, 256, 0, stream>>>(x, part);
    gn_stats_final<<<1, 64, 0, stream>>>(part, stats);
    styleproj_kernel<<<48, 256, 0, stream>>>(style, Wg, bg, Ws, bs, gpb, tmp_s);
    tok_kernel<<<1024, 256, 0, stream>>>(tokens, tmp_s, ln_t_g, ln_t_b, tokb);
    kv_kernel<<<1024, 256, 0, stream>>>(tokb, Wk, bk, Wv, bv, kb16, vt16);
    pos_kernel<<<4096, 256, 0, stream>>>(Wp1, bp1, Wp2, bp2, posb);
    wtrans_kernel<<<64, 256, 0, stream>>>(Wq, wq_t, 256, 256);
    wtrans_kernel<<<64, 256, 0, stream>>>(Wo, wo_t, 256, 256);
    wtrans_kernel<<<128, 256, 0, stream>>>(Wf1, wf1_t, 256, 512);
    wtrans_kernel<<<128, 256, 0, stream>>>(Wf2, wf2_t, 512, 256);
    mega_kernel<<<2048, 256, 0, stream>>>(x, stats, posb,
                                          (const __bf16*)kb16, (const __bf16*)vt16, gpb,
                                          ln_q_g, ln_q_b, ln_f_g, ln_f_b,
                                          (const __bf16*)wq_t, bq,
                                          (const __bf16*)wo_t, bo,
                                          (const __bf16*)wf1_t, bf1,
                                          (const __bf16*)wf2_t, bf2,
                                          gamma, out);
}

// Round 5
// 472.326 us; speedup vs baseline: 8.5522x; 1.4248x over previous
//
#include <hip/hip_runtime.h>
#include <hip/hip_bf16.h>

#define EPSF 1e-5f

typedef __bf16 bf16x8 __attribute__((ext_vector_type(8)));
typedef float  f32x4  __attribute__((ext_vector_type(4)));
#define MFMA16(a, b, c) __builtin_amdgcn_mfma_f32_16x16x32_bf16((a), (b), (c), 0, 0, 0)

__device__ __forceinline__ bf16x8 ld_bf8(const __bf16* p) { return *(const bf16x8*)p; }

__device__ __forceinline__ unsigned short f2bf(float x) {
    unsigned int u = __float_as_uint(x);
    unsigned int r = (u + 0x7fffu + ((u >> 16) & 1u)) >> 16;
    return (unsigned short)r;
}

// ============================================================================
// setup1: role-multiplexed — gn_partial | styleproj | 4x wtrans | pos (16/blk)
// grid = 1024 + 48 + 64 + 64 + 128 + 128 + 256 = 1712
// ============================================================================
__device__ void wtrans_body(const float* __restrict__ W, unsigned short* __restrict__ Wt,
                            int K, int N, int L, int t, float* tile /*32x33*/) {
    int ktiles = K >> 5;
    int kt = L % ktiles, ntl = L / ktiles;
    int k0 = kt * 32, n0 = ntl * 32;
    int tc = t & 31, tr = t >> 5;
#pragma unroll
    for (int j = 0; j < 4; j++)
        tile[(tr + j * 8) * 33 + tc] = W[(size_t)(k0 + tr + j * 8) * N + n0 + tc];
    __syncthreads();
#pragma unroll
    for (int j = 0; j < 4; j++) {
        int r = tr + j * 8;
        Wt[(size_t)(n0 + r) * K + k0 + tc] = f2bf(tile[tc * 33 + r]);
    }
}

__global__ __launch_bounds__(256) void setup1_kernel(
    const float* __restrict__ x, float* __restrict__ part,
    const float* __restrict__ style, const float* __restrict__ Wg,
    const float* __restrict__ bg, const float* __restrict__ Ws,
    const float* __restrict__ bs, float* __restrict__ gp, float* __restrict__ tmp_s,
    const float* __restrict__ Wp1, const float* __restrict__ bp1,
    const float* __restrict__ Wp2, const float* __restrict__ bp2,
    float* __restrict__ pos,
    const float* __restrict__ Wq, const float* __restrict__ Wo,
    const float* __restrict__ Wf1, const float* __restrict__ Wf2,
    unsigned short* __restrict__ wq_t, unsigned short* __restrict__ wo_t,
    unsigned short* __restrict__ wf1_t, unsigned short* __restrict__ wf2_t)
{
    __shared__ float sm[4096];   // 16 KB, carved per role
    const int L = blockIdx.x, t = threadIdx.x;

    if (L < 1024) {
        // ---- GroupNorm partial stats: (b,g) = L>>4, sub = L&15 --------------
        int bg_ = L >> 4, sub = L & 15;
        const float4* p = (const float4*)(x + bg_ * 262144 + sub * 16384);
        float s = 0.f, q = 0.f;
#pragma unroll
        for (int i = 0; i < 16; i++) {
            float4 v = p[i * 256 + t];
            s += v.x + v.y + v.z + v.w;
            q += v.x * v.x + v.y * v.y + v.z * v.z + v.w * v.w;
        }
#pragma unroll
        for (int off = 32; off; off >>= 1) { s += __shfl_down(s, off); q += __shfl_down(q, off); }
        int lane = t & 63, w = t >> 6;
        if (lane == 0) { sm[w * 2] = s; sm[w * 2 + 1] = q; }
        __syncthreads();
        if (t == 0) {
            part[L * 2]     = sm[0] + sm[2] + sm[4] + sm[6];
            part[L * 2 + 1] = sm[1] + sm[3] + sm[5] + sm[7];
        }
    } else if (L < 1072) {
        // ---- style proj ------------------------------------------------------
        int lb = L - 1024, b = lb / 3, role = lb % 3;
        float* st = sm;
        st[t] = style[b * 512 + t];
        st[256 + t] = style[b * 512 + 256 + t];
        __syncthreads();
        if (role < 2) {
            int c = role * 256 + t;
            float acc = 0.f;
            for (int i = 0; i < 512; i++) acc += st[i] * Wg[i * 512 + c];
            gp[b * 512 + c] = acc + bg[c];
        } else {
            float acc = 0.f;
            for (int i = 0; i < 512; i++) acc += st[i] * Ws[i * 256 + t];
            tmp_s[b * 256 + t] = acc + bs[t];
        }
    } else if (L < 1136) {
        wtrans_body(Wq, wq_t, 256, 256, L - 1072, t, sm);
    } else if (L < 1200) {
        wtrans_body(Wo, wo_t, 256, 256, L - 1136, t, sm);
    } else if (L < 1328) {
        wtrans_body(Wf1, wf1_t, 256, 512, L - 1200, t, sm);
    } else if (L < 1456) {
        wtrans_body(Wf2, wf2_t, 512, 256, L - 1328, t, sm);
    } else {
        // ---- pos: 16 positions per block ------------------------------------
        int r = L - 1456, s0 = r * 16;
        float* pe = sm;    // 16 x 256
#pragma unroll
        for (int i = 0; i < 16; i++) {
            int sx = s0 + i;
            float gx = -1.f + 2.f * (float)(sx & 63) * (1.f / 63.f);
            float gy = -1.f + 2.f * (float)(sx >> 6) * (1.f / 63.f);
            float h = gx * Wp1[t] + gy * Wp1[256 + t] + bp1[t];
            pe[i * 256 + t] = h / (1.f + __expf(-h));
        }
        __syncthreads();
        float acc[16];
#pragma unroll
        for (int i = 0; i < 16; i++) acc[i] = 0.f;
#pragma unroll 4
        for (int k = 0; k < 256; k++) {
            float wv = Wp2[k * 256 + t];
#pragma unroll
            for (int i = 0; i < 16; i++) acc[i] += pe[i * 256 + k] * wv;
        }
        float bp = bp2[t];
#pragma unroll
        for (int i = 0; i < 16; i++) pos[(size_t)(s0 + i) * 256 + t] = acc[i] + bp;
    }
}

// ============================================================================
// setup2: tok (blocks 0..1023) + gn_final (block 1024)
// ============================================================================
__global__ __launch_bounds__(256) void setup2_kernel(
    const float* __restrict__ part, float* __restrict__ stats,
    const float* __restrict__ tokens, const float* __restrict__ tmp_s,
    const float* __restrict__ g, const float* __restrict__ bta,
    float* __restrict__ tok)
{
    __shared__ float red[8];
    int blk = blockIdx.x, t = threadIdx.x;
    if (blk == 1024) {
        if (t < 64) {
            float s = 0.f, q = 0.f;
            for (int i = 0; i < 16; i++) { s += part[(t * 16 + i) * 2]; q += part[(t * 16 + i) * 2 + 1]; }
            float m   = s * (1.f / 262144.f);
            float var = q * (1.f / 262144.f) - m * m;
            stats[t]      = m;
            stats[64 + t] = rsqrtf(var + EPSF);
        }
        return;
    }
    int b = blk >> 6, tk = blk & 63;
    float val = tokens[tk * 256 + t] + tmp_s[b * 256 + t];
    float s = val, q = val * val;
#pragma unroll
    for (int off = 32; off; off >>= 1) { s += __shfl_down(s, off); q += __shfl_down(q, off); }
    int lane = t & 63, w = t >> 6;
    if (lane == 0) { red[w * 2] = s; red[w * 2 + 1] = q; }
    __syncthreads();
    s = red[0] + red[2] + red[4] + red[6];
    q = red[1] + red[3] + red[5] + red[7];
    float m = s * (1.f / 256.f);
    float var = q * (1.f / 256.f) - m * m;
    float r = rsqrtf(var + EPSF);
    tok[(b * 64 + tk) * 256 + t] = (val - m) * r * g[t] + bta[t];
}

// ============================================================================
// setup3: k -> bf16 [tok][256]; v -> transposed bf16 [b][ch][tok]
// ============================================================================
__global__ __launch_bounds__(256) void kv_kernel(const float* __restrict__ tok,
                                                 const float* __restrict__ Wk,
                                                 const float* __restrict__ bk,
                                                 const float* __restrict__ Wv,
                                                 const float* __restrict__ bv,
                                                 unsigned short* __restrict__ kb16,
                                                 unsigned short* __restrict__ vt16) {
    __shared__ float tr[256];
    int blk = blockIdx.x, t = threadIdx.x;   // 1024 = b*64+tok
    int b = blk >> 6, tkn = blk & 63;
    tr[t] = tok[blk * 256 + t];
    __syncthreads();
    float ak = 0.f, av = 0.f;
    for (int i = 0; i < 256; i++) {
        float tv = tr[i];
        ak += tv * Wk[i * 256 + t];
        av += tv * Wv[i * 256 + t];
    }
    kb16[(size_t)blk * 256 + t] = f2bf(ak + bk[t]);
    vt16[((size_t)(b * 256 + t)) * 64 + tkn] = f2bf(av + bv[t]);
}

// ============================================================================
// Mega kernel. Block = (b, 32-row s-tile). LDS = 52,224 B -> 3 blocks/CU.
// Wave w owns: GEMM cols [w*64, w*64+64), attention head w, both 16-row tiles.
// ============================================================================
__global__ __launch_bounds__(256, 3) void mega_kernel(
    const float* __restrict__ x, const float* __restrict__ stats,
    const float* __restrict__ pos,
    const __bf16* __restrict__ kb, const __bf16* __restrict__ vt,
    const float* __restrict__ gp,
    const float* __restrict__ lnq_g, const float* __restrict__ lnq_b,
    const float* __restrict__ lnf_g, const float* __restrict__ lnf_b,
    const __bf16* __restrict__ Wq_t, const float* __restrict__ bq,
    const __bf16* __restrict__ Wo_t, const float* __restrict__ bo,
    const __bf16* __restrict__ Wf1_t, const float* __restrict__ bf1,
    const __bf16* __restrict__ Wf2_t, const float* __restrict__ bf2,
    const float* __restrict__ gamma, float* __restrict__ out)
{
    __shared__ __align__(16) unsigned char smraw[52224];
    __bf16* Ab = (__bf16*)smraw;               // 32*264 bf16 = 16,896 B
    __bf16* Sb = (__bf16*)(smraw + 16896);     // 32*264 bf16 = 16,896 B (sc residual)
    __bf16* Ps = (__bf16*)(smraw + 33792);     // 4 waves * 32*72 bf16 = 18,432 B
    float* psum   = (float*)(smraw + 33792);   // overlay (stats phases only)
    float* psq    = (float*)(smraw + 33792 + 1024);
    float* rowred = (float*)(smraw + 33792 + 2048);

    const int blk  = blockIdx.x;        // 2048 = 16 b * 128 tiles
    const int b    = blk >> 7;
    const int s0   = (blk & 127) * 32;
    const int t    = threadIdx.x;
    const int w    = t >> 6;
    const int lane = t & 63;
    const int quad = lane >> 4;
    const int l16  = lane & 15;

    const float mg = stats[b * 4 + (t >> 6)];
    const float rg = stats[64 + b * 4 + (t >> 6)];
    const f32x4 z4 = {0.f, 0.f, 0.f, 0.f};

    // ---- S1: Ab = bf16(GN(x)+pos); row stats; LN_q in place ------------------
    {
        const float4* xp = (const float4*)(x + (size_t)(b * 256 + t) * 4096 + s0);
        float xv[32];
#pragma unroll
        for (int i = 0; i < 8; i++) {
            float4 v = xp[i];
            xv[4*i] = v.x; xv[4*i+1] = v.y; xv[4*i+2] = v.z; xv[4*i+3] = v.w;
        }
#pragma unroll
        for (int i = 0; i < 32; i++)
            Ab[i * 264 + t] = (__bf16)((xv[i] - mg) * rg + pos[(size_t)(s0 + i) * 256 + t]);
    }
    __syncthreads();
    {
        int sl = t & 31, cg = t >> 5;
        float s = 0.f, q = 0.f;
#pragma unroll
        for (int j = 0; j < 4; j++) {
            bf16x8 v8 = ld_bf8(&Ab[sl * 264 + cg * 32 + j * 8]);
#pragma unroll
            for (int e = 0; e < 8; e++) { float f = (float)v8[e]; s += f; q += f * f; }
        }
        psum[cg * 32 + sl] = s; psq[cg * 32 + sl] = q;
    }
    __syncthreads();
    if (t < 32) {
        float S = 0.f, Q = 0.f;
        for (int p = 0; p < 8; p++) { S += psum[p * 32 + t]; Q += psq[p * 32 + t]; }
        float m = S * (1.f / 256.f);
        float var = Q * (1.f / 256.f) - m * m;
        rowred[t * 2] = m; rowred[t * 2 + 1] = rsqrtf(var + EPSF);
    }
    __syncthreads();
    {
        float gq = lnq_g[t], bqv = lnq_b[t];
#pragma unroll
        for (int i = 0; i < 32; i++) {
            float v = (float)Ab[i * 264 + t];
            Ab[i * 264 + t] = (__bf16)((v - rowred[i * 2]) * rowred[i * 2 + 1] * gq + bqv);
        }
    }
    __syncthreads();

    // ---- S2: q = Ab @ Wq + bq -> Ab (wave: 32 rows x 64 cols, no B dup) ------
    {
        bf16x8 af[2][8];
#pragma unroll
        for (int rt = 0; rt < 2; rt++)
#pragma unroll
            for (int ks = 0; ks < 8; ks++)
                af[rt][ks] = ld_bf8(&Ab[(rt * 16 + l16) * 264 + ks * 32 + quad * 8]);
        __syncthreads();   // all waves' A-frags loaded before Ab overwrite
#pragma unroll
        for (int nt = 0; nt < 4; nt++) {
            int n = w * 64 + nt * 16 + l16;
            f32x4 a0 = z4, a1 = z4;
#pragma unroll
            for (int ks = 0; ks < 8; ks++) {
                bf16x8 bv = ld_bf8(&Wq_t[(size_t)n * 256 + ks * 32 + quad * 8]);
                a0 = MFMA16(af[0][ks], bv, a0);
                a1 = MFMA16(af[1][ks], bv, a1);
            }
            float bias = bq[n];
#pragma unroll
            for (int r = 0; r < 4; r++) {
                Ab[(quad * 4 + r) * 264 + n]        = (__bf16)(a0[r] + bias);
                Ab[(16 + quad * 4 + r) * 264 + n]   = (__bf16)(a1[r] + bias);
            }
        }
    }
    // no barrier: S3 wave w reads exactly the cols wave w just wrote

    // ---- S3: attention, head = w, 32 rows ------------------------------------
    {
        const int h = w;
        __bf16* Psw = Ps + w * 32 * 72;
        bf16x8 qa[2][2];
#pragma unroll
        for (int rt = 0; rt < 2; rt++)
#pragma unroll
            for (int k0 = 0; k0 < 2; k0++)
                qa[rt][k0] = ld_bf8(&Ab[(rt * 16 + l16) * 264 + h * 64 + k0 * 32 + quad * 8]);
        f32x4 sa[2][4];
#pragma unroll
        for (int rt = 0; rt < 2; rt++)
#pragma unroll
            for (int nt = 0; nt < 4; nt++) sa[rt][nt] = z4;
#pragma unroll
        for (int nt = 0; nt < 4; nt++)
#pragma unroll
            for (int k0 = 0; k0 < 2; k0++) {
                bf16x8 kv8 = ld_bf8(&kb[((size_t)(b * 64 + nt * 16 + l16)) * 256 + h * 64 + k0 * 32 + quad * 8]);
                sa[0][nt] = MFMA16(qa[0][k0], kv8, sa[0][nt]);
                sa[1][nt] = MFMA16(qa[1][k0], kv8, sa[1][nt]);
            }
        // softmax per row; P -> Psw (bf16)
#pragma unroll
        for (int rt = 0; rt < 2; rt++)
#pragma unroll
            for (int r = 0; r < 4; r++) {
                float e0 = sa[rt][0][r] * 0.25f, e1 = sa[rt][1][r] * 0.25f;
                float e2 = sa[rt][2][r] * 0.25f, e3 = sa[rt][3][r] * 0.25f;
                float mx = fmaxf(fmaxf(e0, e1), fmaxf(e2, e3));
#pragma unroll
                for (int off = 1; off < 16; off <<= 1) mx = fmaxf(mx, __shfl_xor(mx, off));
                e0 = __expf(e0 - mx); e1 = __expf(e1 - mx);
                e2 = __expf(e2 - mx); e3 = __expf(e3 - mx);
                float sum = e0 + e1 + e2 + e3;
#pragma unroll
                for (int off = 1; off < 16; off <<= 1) sum += __shfl_xor(sum, off);
                float inv = 1.f / sum;
                int row = rt * 16 + quad * 4 + r;
                Psw[row * 72 +  0 + l16] = (__bf16)(e0 * inv);
                Psw[row * 72 + 16 + l16] = (__bf16)(e1 * inv);
                Psw[row * 72 + 32 + l16] = (__bf16)(e2 * inv);
                Psw[row * 72 + 48 + l16] = (__bf16)(e3 * inv);
            }
        // O = P @ V_h -> Ab cols [h*64, h*64+64)  (same-wave LDS, in order)
        bf16x8 pa[2][2];
#pragma unroll
        for (int rt = 0; rt < 2; rt++)
#pragma unroll
            for (int k0 = 0; k0 < 2; k0++)
                pa[rt][k0] = ld_bf8(&Psw[(rt * 16 + l16) * 72 + k0 * 32 + quad * 8]);
#pragma unroll
        for (int nt = 0; nt < 4; nt++) {
            f32x4 o0 = z4, o1 = z4;
#pragma unroll
            for (int k0 = 0; k0 < 2; k0++) {
                bf16x8 vv = ld_bf8(&vt[((size_t)(b * 256 + h * 64 + nt * 16 + l16)) * 64 + k0 * 32 + quad * 8]);
                o0 = MFMA16(pa[0][k0], vv, o0);
                o1 = MFMA16(pa[1][k0], vv, o1);
            }
#pragma unroll
            for (int r = 0; r < 4; r++) {
                Ab[(quad * 4 + r) * 264 + h * 64 + nt * 16 + l16]      = (__bf16)o0[r];
                Ab[(16 + quad * 4 + r) * 264 + h * 64 + nt * 16 + l16] = (__bf16)o1[r];
            }
        }
    }
    __syncthreads();

    // ---- S4: sc = Ab @ Wo + bo -> Sb -----------------------------------------
    {
        bf16x8 af[2][8];
#pragma unroll
        for (int rt = 0; rt < 2; rt++)
#pragma unroll
            for (int ks = 0; ks < 8; ks++)
                af[rt][ks] = ld_bf8(&Ab[(rt * 16 + l16) * 264 + ks * 32 + quad * 8]);
#pragma unroll
        for (int nt = 0; nt < 4; nt++) {
            int n = w * 64 + nt * 16 + l16;
            f32x4 a0 = z4, a1 = z4;
#pragma unroll
            for (int ks = 0; ks < 8; ks++) {
                bf16x8 bv = ld_bf8(&Wo_t[(size_t)n * 256 + ks * 32 + quad * 8]);
                a0 = MFMA16(af[0][ks], bv, a0);
                a1 = MFMA16(af[1][ks], bv, a1);
            }
            float bias = bo[n];
#pragma unroll
            for (int r = 0; r < 4; r++) {
                Sb[(quad * 4 + r) * 264 + n]      = (__bf16)(a0[r] + bias);
                Sb[(16 + quad * 4 + r) * 264 + n] = (__bf16)(a1[r] + bias);
            }
        }
    }
    __syncthreads();

    // ---- S5: FFN. stats on Sb; Ab = bf16(LN_f(Sb)); 8 x 64-col h1 chunks -----
    {
        int sl = t & 31, cg = t >> 5;
        float s = 0.f, q = 0.f;
#pragma unroll
        for (int j = 0; j < 4; j++) {
            bf16x8 v8 = ld_bf8(&Sb[sl * 264 + cg * 32 + j * 8]);
#pragma unroll
            for (int e = 0; e < 8; e++) { float f = (float)v8[e]; s += f; q += f * f; }
        }
        psum[cg * 32 + sl] = s; psq[cg * 32 + sl] = q;
    }
    __syncthreads();
    if (t < 32) {
        float S = 0.f, Q = 0.f;
        for (int p = 0; p < 8; p++) { S += psum[p * 32 + t]; Q += psq[p * 32 + t]; }
        float m = S * (1.f / 256.f);
        float var = Q * (1.f / 256.f) - m * m;
        rowred[t * 2] = m; rowred[t * 2 + 1] = rsqrtf(var + EPSF);
    }
    __syncthreads();
    {
        float gf = lnf_g[t], bff = lnf_b[t];
#pragma unroll
        for (int i = 0; i < 32; i++) {
            float v = (float)Sb[i * 264 + t];
            Ab[i * 264 + t] = (__bf16)((v - rowred[i * 2]) * rowred[i * 2 + 1] * gf + bff);
        }
    }
    __syncthreads();
    {
        __bf16* Hb = Ps;   // 32 x 72 chunk bounce (rowred dead after this barrier)
        bf16x8 fa[2][8];
#pragma unroll
        for (int rt = 0; rt < 2; rt++)
#pragma unroll
            for (int ks = 0; ks < 8; ks++)
                fa[rt][ks] = ld_bf8(&Ab[(rt * 16 + l16) * 264 + ks * 32 + quad * 8]);
        f32x4 acc2[2][4];
#pragma unroll
        for (int rt = 0; rt < 2; rt++)
#pragma unroll
            for (int nt = 0; nt < 4; nt++) acc2[rt][nt] = z4;

        for (int cc = 0; cc < 8; cc++) {
            // FF1: wave computes h1 cols cc*64 + w*16 .. +16 for all 32 rows
            int n1 = cc * 64 + w * 16 + l16;
            f32x4 h0 = z4, h1 = z4;
#pragma unroll
            for (int ks = 0; ks < 8; ks++) {
                bf16x8 bv = ld_bf8(&Wf1_t[(size_t)n1 * 256 + ks * 32 + quad * 8]);
                h0 = MFMA16(fa[0][ks], bv, h0);
                h1 = MFMA16(fa[1][ks], bv, h1);
            }
            float b1v = bf1[n1];
            __syncthreads();   // prior chunk's Hb reads complete
#pragma unroll
            for (int r = 0; r < 4; r++) {
                float u0 = h0[r] + b1v;
                float u1 = h1[r] + b1v;
                Hb[(quad * 4 + r) * 72 + w * 16 + l16]      = (__bf16)(u0 / (1.f + __expf(-u0)));
                Hb[(16 + quad * 4 + r) * 72 + w * 16 + l16] = (__bf16)(u1 / (1.f + __expf(-u1)));
            }
            __syncthreads();
            // FF2 accumulate over this 64-K chunk
            bf16x8 ha[2][2];
#pragma unroll
            for (int rt = 0; rt < 2; rt++)
#pragma unroll
                for (int k0 = 0; k0 < 2; k0++)
                    ha[rt][k0] = ld_bf8(&Hb[(rt * 16 + l16) * 72 + k0 * 32 + quad * 8]);
#pragma unroll
            for (int nt = 0; nt < 4; nt++) {
                int n2 = w * 64 + nt * 16 + l16;
#pragma unroll
                for (int k0 = 0; k0 < 2; k0++) {
                    bf16x8 bv = ld_bf8(&Wf2_t[(size_t)n2 * 512 + cc * 64 + k0 * 32 + quad * 8]);
                    acc2[0][nt] = MFMA16(ha[0][k0], bv, acc2[0][nt]);
                    acc2[1][nt] = MFMA16(ha[1][k0], bv, acc2[1][nt]);
                }
            }
        }
        // sc_final = sc + ffn + bf2 -> Sb (same-wave cols)
#pragma unroll
        for (int nt = 0; nt < 4; nt++) {
            int n = w * 64 + nt * 16 + l16;
            float b2 = bf2[n];
#pragma unroll
            for (int r = 0; r < 4; r++) {
                int i0 = (quad * 4 + r) * 264 + n;
                int i1 = (16 + quad * 4 + r) * 264 + n;
                Sb[i0] = (__bf16)((float)Sb[i0] + acc2[0][nt][r] + b2);
                Sb[i1] = (__bf16)((float)Sb[i1] + acc2[1][nt][r] + b2);
            }
        }
    }
    __syncthreads();

    // ---- S6: out[b,c,s] = GN(x)*scale + shift + sc*gamma ---------------------
    {
        const float scl = gp[b * 512 + t];
        const float sft = gp[b * 512 + 256 + t];
        const float gm  = gamma[t];
        const float4* xp = (const float4*)(x + (size_t)(b * 256 + t) * 4096 + s0);
        float4* op = (float4*)(out + (size_t)(b * 256 + t) * 4096 + s0);
#pragma unroll
        for (int ii = 0; ii < 8; ii++) {
            float4 xv = xp[ii];
            float4 o;
            o.x = (xv.x - mg) * rg * scl + sft + (float)Sb[(ii * 4 + 0) * 264 + t] * gm;
            o.y = (xv.y - mg) * rg * scl + sft + (float)Sb[(ii * 4 + 1) * 264 + t] * gm;
            o.z = (xv.z - mg) * rg * scl + sft + (float)Sb[(ii * 4 + 2) * 264 + t] * gm;
            o.w = (xv.w - mg) * rg * scl + sft + (float)Sb[(ii * 4 + 3) * 264 + t] * gm;
            op[ii] = o;
        }
    }
}

// ============================================================================
extern "C" void kernel_launch(void* const* d_in, const int* in_sizes, int n_in,
                              void* d_out, int out_size, void* d_ws, size_t ws_size,
                              hipStream_t stream) {
    (void)in_sizes; (void)n_in; (void)out_size; (void)ws_size;
    const float* x      = (const float*)d_in[0];
    const float* style  = (const float*)d_in[1];
    const float* Wg     = (const float*)d_in[2];
    const float* bg     = (const float*)d_in[3];
    const float* tokens = (const float*)d_in[4];
    const float* Ws     = (const float*)d_in[5];
    const float* bs     = (const float*)d_in[6];
    const float* Wp1    = (const float*)d_in[7];
    const float* bp1    = (const float*)d_in[8];
    const float* Wp2    = (const float*)d_in[9];
    const float* bp2    = (const float*)d_in[10];
    const float* ln_t_g = (const float*)d_in[11];
    const float* ln_t_b = (const float*)d_in[12];
    const float* ln_q_g = (const float*)d_in[13];
    const float* ln_q_b = (const float*)d_in[14];
    const float* ln_f_g = (const float*)d_in[15];
    const float* ln_f_b = (const float*)d_in[16];
    const float* Wq     = (const float*)d_in[17];
    const float* bq     = (const float*)d_in[18];
    const float* Wk     = (const float*)d_in[19];
    const float* bk     = (const float*)d_in[20];
    const float* Wv     = (const float*)d_in[21];
    const float* bv     = (const float*)d_in[22];
    const float* Wo     = (const float*)d_in[23];
    const float* bo     = (const float*)d_in[24];
    const float* Wf1    = (const float*)d_in[25];
    const float* bf1    = (const float*)d_in[26];
    const float* Wf2    = (const float*)d_in[27];
    const float* bf2    = (const float*)d_in[28];
    const float* gamma  = (const float*)d_in[29];
    float* out = (float*)d_out;

    // d_ws layout (~7.1 MB)
    float* ws = (float*)d_ws;
    float* part  = ws;               // 2048
    float* stats = part  + 2048;     // 128
    float* gpb   = stats + 128;      // 8192
    float* tmp_s = gpb   + 8192;     // 4096
    float* tokb  = tmp_s + 4096;     // 262144
    float* posb  = tokb  + 262144;   // 1048576
    unsigned short* kb16  = (unsigned short*)(posb + 1048576); // 262144 bf16
    unsigned short* vt16  = kb16  + 262144;                    // 262144
    unsigned short* wq_t  = vt16  + 262144;                    // 65536
    unsigned short* wo_t  = wq_t  + 65536;                     // 65536
    unsigned short* wf1_t = wo_t  + 65536;                     // 131072
    unsigned short* wf2_t = wf1_t + 131072;                    // 131072

    setup1_kernel<<<1712, 256, 0, stream>>>(x, part, style, Wg, bg, Ws, bs, gpb, tmp_s,
                                            Wp1, bp1, Wp2, bp2, posb,
                                            Wq, Wo, Wf1, Wf2,
                                            wq_t, wo_t, wf1_t, wf2_t);
    setup2_kernel<<<1025, 256, 0, stream>>>(part, stats, tokens, tmp_s, ln_t_g, ln_t_b, tokb);
    kv_kernel<<<1024, 256, 0, stream>>>(tokb, Wk, bk, Wv, bv, kb16, vt16);
    mega_kernel<<<2048, 256, 0, stream>>>(x, stats, posb,
                                          (const __bf16*)kb16, (const __bf16*)vt16, gpb,
                                          ln_q_g, ln_q_b, ln_f_g, ln_f_b,
                                          (const __bf16*)wq_t, bq,
                                          (const __bf16*)wo_t, bo,
                                          (const __bf16*)wf1_t, bf1,
                                          (const __bf16*)wf2_t, bf2,
                                          gamma, out);
}